// Round 2
// baseline (775.018 us; speedup 1.0000x reference)
//
#include <hip/hip_runtime.h>

typedef __bf16 bf16;
typedef __bf16 bf16x8 __attribute__((ext_vector_type(8)));
typedef __bf16 bf16x4 __attribute__((ext_vector_type(4)));
typedef float  f32x4  __attribute__((ext_vector_type(4)));

#define B_ 2
#define S_ 2048
#define D_ 1024
#define H_ 16
#define HD_ 64
#define MROWS_ (B_*S_)   /* 4096 */

// ---------------------------------------------------------------------------
// Kernel 1: convert query/key/value fp32 -> bf16 (A-operands for projections)
// ---------------------------------------------------------------------------
__global__ __launch_bounds__(256) void convert_kernel(
    const float* __restrict__ q, const float* __restrict__ k, const float* __restrict__ v,
    bf16* __restrict__ qx, bf16* __restrict__ kx, bf16* __restrict__ vx)
{
    size_t i = ((size_t)blockIdx.x * 256 + threadIdx.x) * 4;
    float4 a = *(const float4*)(q + i);
    float4 b = *(const float4*)(k + i);
    float4 c = *(const float4*)(v + i);
    bf16x4 oa = { (bf16)a.x, (bf16)a.y, (bf16)a.z, (bf16)a.w };
    bf16x4 ob = { (bf16)b.x, (bf16)b.y, (bf16)b.z, (bf16)b.w };
    bf16x4 oc = { (bf16)c.x, (bf16)c.y, (bf16)c.z, (bf16)c.w };
    *(bf16x4*)(qx + i) = oa;
    *(bf16x4*)(kx + i) = ob;
    *(bf16x4*)(vx + i) = oc;
}

// ---------------------------------------------------------------------------
// Kernel 2: weight transpose + convert: W [K=1024,N=1024] fp32 -> WT [N,K] bf16
// grid (N/32, K/32, 4), block (32,8)
// ---------------------------------------------------------------------------
__global__ __launch_bounds__(256) void wtrans_kernel(
    const float* __restrict__ W0, const float* __restrict__ W1,
    const float* __restrict__ W2, const float* __restrict__ W3,
    bf16* __restrict__ T0, bf16* __restrict__ T1,
    bf16* __restrict__ T2, bf16* __restrict__ T3)
{
    int z = blockIdx.z;
    const float* W = z == 0 ? W0 : (z == 1 ? W1 : (z == 2 ? W2 : W3));
    bf16* T = z == 0 ? T0 : (z == 1 ? T1 : (z == 2 ? T2 : T3));
    __shared__ float tile[32][33];
    int n0 = blockIdx.x * 32, k0 = blockIdx.y * 32;
    int tx = threadIdx.x, ty = threadIdx.y;
#pragma unroll
    for (int r = 0; r < 4; r++)
        tile[ty + r * 8][tx] = W[(size_t)(k0 + ty + r * 8) * D_ + n0 + tx];
    __syncthreads();
#pragma unroll
    for (int r = 0; r < 4; r++)
        T[(size_t)(n0 + ty + r * 8) * D_ + k0 + tx] = (bf16)tile[tx][ty + r * 8];
}

// ---------------------------------------------------------------------------
// Kernel 3: GEMM + bias.  C[M,N] = A[M,K] @ BT[N,K]^T + bias.
// A,BT bf16; OUT_MODE 0 -> bf16 out, 1 -> fp32 out.
// 128x128 tile, BK=32, 256 threads (4 waves, 2x2 quadrants of 64x64).
// grid (N/128, M/128, z) ; z selects one of up to 3 problem instances.
// ---------------------------------------------------------------------------
template <int OUT_MODE>
__global__ __launch_bounds__(256) void gemm_bias_kernel(
    const bf16* __restrict__ A0, const bf16* __restrict__ A1, const bf16* __restrict__ A2,
    const bf16* __restrict__ B0, const bf16* __restrict__ B1, const bf16* __restrict__ B2,
    const float* __restrict__ bias0, const float* __restrict__ bias1, const float* __restrict__ bias2,
    void* __restrict__ out0, void* __restrict__ out1, void* __restrict__ out2)
{
    constexpr int K = 1024, N = 1024;
    int z = blockIdx.z;
    const bf16* A = z == 0 ? A0 : (z == 1 ? A1 : A2);
    const bf16* Bt = z == 0 ? B0 : (z == 1 ? B1 : B2);
    const float* bias = z == 0 ? bias0 : (z == 1 ? bias1 : bias2);
    void* out = z == 0 ? out0 : (z == 1 ? out1 : out2);

    // pitch 40 bf16 = 80B: 16B-aligned chunks, rows shift 20 words -> conflict-free frag reads
    __shared__ bf16 sA[128][40];
    __shared__ bf16 sB[128][40];

    int tid = threadIdx.x, wave = tid >> 6, lane = tid & 63;
    int lrow = lane & 15, quad = lane >> 4;
    int m0 = blockIdx.y * 128, n0 = blockIdx.x * 128;
    int rb = (wave & 1) * 64, cb = (wave >> 1) * 64;

    f32x4 acc[4][4] = {};

    for (int k0 = 0; k0 < K; k0 += 32) {
        __syncthreads();
        // stage full 128x32 tiles: 512 uint4 per buffer, 2 per thread
#pragma unroll
        for (int it = 0; it < 2; it++) {
            int idx = tid + it * 256;          // 0..511
            int r = idx >> 2, c = (idx & 3) * 8;
            *(uint4*)&sA[r][c] = *(const uint4*)(A + (size_t)(m0 + r) * K + k0 + c);
            *(uint4*)&sB[r][c] = *(const uint4*)(Bt + (size_t)(n0 + r) * K + k0 + c);
        }
        __syncthreads();
        bf16x8 af[4], bfv[4];
#pragma unroll
        for (int t = 0; t < 4; t++) {
            af[t]  = *(const bf16x8*)&sA[rb + t * 16 + lrow][quad * 8];
            bfv[t] = *(const bf16x8*)&sB[cb + t * 16 + lrow][quad * 8];
        }
#pragma unroll
        for (int rt = 0; rt < 4; rt++)
#pragma unroll
            for (int ct = 0; ct < 4; ct++)
                acc[rt][ct] = __builtin_amdgcn_mfma_f32_16x16x32_bf16(af[rt], bfv[ct], acc[rt][ct], 0, 0, 0);
    }

#pragma unroll
    for (int ct = 0; ct < 4; ct++) {
        int n = n0 + cb + ct * 16 + lrow;
        float bv = bias[n];
#pragma unroll
        for (int rt = 0; rt < 4; rt++) {
            int m = m0 + rb + rt * 16 + quad * 4;
#pragma unroll
            for (int rr = 0; rr < 4; rr++) {
                float val = acc[rt][ct][rr] + bv;
                if (OUT_MODE == 0) ((bf16*)out)[(size_t)(m + rr) * N + n] = (bf16)val;
                else               ((float*)out)[(size_t)(m + rr) * N + n] = val;
            }
        }
    }
}

// ---------------------------------------------------------------------------
// Kernel 4: repack V: vp [B,S,D] bf16 -> vT [B,H,HD,S] bf16 (per-head transpose)
// grid (S/64, B*H), block 256
// ---------------------------------------------------------------------------
__global__ __launch_bounds__(256) void vtrans_kernel(
    const bf16* __restrict__ vp, bf16* __restrict__ vT)
{
    __shared__ bf16 tile[64][72];  // pitch 144B, 16B-aligned
    int s0 = blockIdx.x * 64;
    int bh = blockIdx.y;
    int b = bh >> 4, h = bh & 15;
    int tid = threadIdx.x;
#pragma unroll
    for (int it = 0; it < 2; it++) {
        int idx = tid + it * 256;         // 0..511
        int s = idx >> 3, c = (idx & 7) * 8;
        *(uint4*)&tile[s][c] = *(const uint4*)&vp[(size_t)(b * S_ + s0 + s) * D_ + h * HD_ + c];
    }
    __syncthreads();
#pragma unroll
    for (int it = 0; it < 2; it++) {
        int idx = tid + it * 256;
        int d = idx >> 3, c = (idx & 7) * 8;
        bf16x8 t;
#pragma unroll
        for (int j = 0; j < 8; j++) t[j] = tile[c + j][d];
        *(bf16x8*)&vT[(size_t)(bh * HD_ + d) * S_ + s0 + c] = t;
    }
}

// ---------------------------------------------------------------------------
// Kernel 5: attention. Per block: 64 query rows of one (b,h).
// Pass 1: rowsums of exp(qk/8) (no max needed: |logits| <= ~2.5).
// Pass 2: recompute scores, write normalized attn fp32, PV via LDS P round-trip.
// grid (S/64, B*H), block 256 (4 waves; wave w owns q-rows w*16..w*16+15)
// ---------------------------------------------------------------------------
__global__ __launch_bounds__(256) void attn_kernel(
    const bf16* __restrict__ qp, const bf16* __restrict__ kp, const bf16* __restrict__ vT,
    float* __restrict__ attn, bf16* __restrict__ op)
{
    __shared__ bf16 sQ[64][72];
    __shared__ bf16 sK[128][72];
    __shared__ bf16 sVT[64][136];
    __shared__ bf16 sP[64][136];
    __shared__ float sInv[64];

    int qt = blockIdx.x, bh = blockIdx.y;
    int b = bh >> 4, h = bh & 15;
    int q0 = qt * 64;
    int tid = threadIdx.x, wave = tid >> 6, lane = tid & 63;
    int lrow = lane & 15, quad = lane >> 4;
    const float scale = 0.125f;  // 1/sqrt(64)

    // ---- load Q tile (64 x 64 bf16) ----
    const size_t qbase = (size_t)(b * S_ + q0) * D_ + h * HD_;
#pragma unroll
    for (int it = 0; it < 2; it++) {
        int idx = tid + it * 256;
        int r = idx >> 3, c = (idx & 7) * 8;
        *(uint4*)&sQ[r][c] = *(const uint4*)&qp[qbase + (size_t)r * D_ + c];
    }
    __syncthreads();
    bf16x8 aq0 = *(const bf16x8*)&sQ[wave * 16 + lrow][quad * 8];
    bf16x8 aq1 = *(const bf16x8*)&sQ[wave * 16 + lrow][32 + quad * 8];

    const size_t kbase0 = (size_t)(b * S_) * D_ + h * HD_;

    // ---- PASS 1: rowsums ----
    float rsum[4] = {0.f, 0.f, 0.f, 0.f};
    for (int kt = 0; kt < 16; kt++) {
        __syncthreads();
#pragma unroll
        for (int it = 0; it < 4; it++) {
            int idx = tid + it * 256;
            int r = idx >> 3, c = (idx & 7) * 8;
            *(uint4*)&sK[r][c] = *(const uint4*)&kp[kbase0 + (size_t)(kt * 128 + r) * D_ + c];
        }
        __syncthreads();
#pragma unroll
        for (int ct = 0; ct < 8; ct++) {
            f32x4 s = {0.f, 0.f, 0.f, 0.f};
            bf16x8 b0 = *(const bf16x8*)&sK[ct * 16 + lrow][quad * 8];
            bf16x8 b1 = *(const bf16x8*)&sK[ct * 16 + lrow][32 + quad * 8];
            s = __builtin_amdgcn_mfma_f32_16x16x32_bf16(aq0, b0, s, 0, 0, 0);
            s = __builtin_amdgcn_mfma_f32_16x16x32_bf16(aq1, b1, s, 0, 0, 0);
#pragma unroll
            for (int r = 0; r < 4; r++) rsum[r] += __expf(s[r] * scale);
        }
    }
    // reduce across the 16 lanes that share the same 4 q-rows
#pragma unroll
    for (int off = 1; off < 16; off <<= 1)
#pragma unroll
        for (int r = 0; r < 4; r++) rsum[r] += __shfl_xor(rsum[r], off);
    if (lrow == 0) {
#pragma unroll
        for (int r = 0; r < 4; r++) sInv[wave * 16 + quad * 4 + r] = 1.0f / rsum[r];
    }
    __syncthreads();
    float inv[4];
#pragma unroll
    for (int r = 0; r < 4; r++) inv[r] = sInv[wave * 16 + quad * 4 + r];

    // ---- PASS 2: normalized attn write + PV ----
    f32x4 oacc[4] = {};
    float* attn_base = attn + ((size_t)bh * S_ + q0) * S_;
    const size_t vbase = (size_t)(bh * HD_) * S_;
    for (int kt = 0; kt < 16; kt++) {
        __syncthreads();
#pragma unroll
        for (int it = 0; it < 4; it++) {
            int idx = tid + it * 256;
            int r = idx >> 3, c = (idx & 7) * 8;
            *(uint4*)&sK[r][c] = *(const uint4*)&kp[kbase0 + (size_t)(kt * 128 + r) * D_ + c];
        }
#pragma unroll
        for (int it = 0; it < 4; it++) {
            int idx = tid + it * 256;
            int d = idx >> 4, c = (idx & 15) * 8;
            *(uint4*)&sVT[d][c] = *(const uint4*)&vT[vbase + (size_t)d * S_ + kt * 128 + c];
        }
        __syncthreads();
#pragma unroll
        for (int ct = 0; ct < 8; ct++) {
            f32x4 s = {0.f, 0.f, 0.f, 0.f};
            bf16x8 b0 = *(const bf16x8*)&sK[ct * 16 + lrow][quad * 8];
            bf16x8 b1 = *(const bf16x8*)&sK[ct * 16 + lrow][32 + quad * 8];
            s = __builtin_amdgcn_mfma_f32_16x16x32_bf16(aq0, b0, s, 0, 0, 0);
            s = __builtin_amdgcn_mfma_f32_16x16x32_bf16(aq1, b1, s, 0, 0, 0);
            int key_local = ct * 16 + lrow;
#pragma unroll
            for (int r = 0; r < 4; r++) {
                float e = __expf(s[r] * scale) * inv[r];
                int qrow = wave * 16 + quad * 4 + r;
                attn_base[(size_t)qrow * S_ + kt * 128 + key_local] = e;
                sP[qrow][key_local] = (bf16)e;
            }
        }
        // PV: each wave reads only its own sP rows (same-wave LDS dep; compiler waits)
        bf16x8 ap[4];
#pragma unroll
        for (int ks = 0; ks < 4; ks++)
            ap[ks] = *(const bf16x8*)&sP[wave * 16 + lrow][ks * 32 + quad * 8];
#pragma unroll
        for (int dt = 0; dt < 4; dt++)
#pragma unroll
            for (int ks = 0; ks < 4; ks++) {
                bf16x8 bv = *(const bf16x8*)&sVT[dt * 16 + lrow][ks * 32 + quad * 8];
                oacc[dt] = __builtin_amdgcn_mfma_f32_16x16x32_bf16(ap[ks], bv, oacc[dt], 0, 0, 0);
            }
    }

    // epilogue: O already normalized (P was normalized); store bf16 [B,S,D]
#pragma unroll
    for (int dt = 0; dt < 4; dt++)
#pragma unroll
        for (int r = 0; r < 4; r++) {
            int qrow = q0 + wave * 16 + quad * 4 + r;
            op[(size_t)(b * S_ + qrow) * D_ + h * HD_ + dt * 16 + lrow] = (bf16)oacc[dt][r];
        }
}

// ---------------------------------------------------------------------------
extern "C" void kernel_launch(void* const* d_in, const int* in_sizes, int n_in,
                              void* d_out, int out_size, void* d_ws, size_t ws_size,
                              hipStream_t stream)
{
    const float* query = (const float*)d_in[0];
    const float* key_  = (const float*)d_in[1];
    const float* value = (const float*)d_in[2];
    const float* Wq = (const float*)d_in[3];
    const float* bq = (const float*)d_in[4];
    const float* Wk = (const float*)d_in[5];
    const float* bk = (const float*)d_in[6];
    const float* Wv = (const float*)d_in[7];
    const float* bv = (const float*)d_in[8];
    const float* Wo = (const float*)d_in[9];
    const float* bo = (const float*)d_in[10];

    float* out  = (float*)d_out;                         // [B,S,D]
    float* attn = out + (size_t)B_ * S_ * D_;            // [B,H,S,S]

    char* ws = (char*)d_ws;
    const size_t SZ_BSD = (size_t)MROWS_ * D_ * sizeof(bf16);  // 8 MiB
    const size_t SZ_W   = (size_t)D_ * D_ * sizeof(bf16);      // 2 MiB
    bf16* qx  = (bf16*)(ws + 0 * SZ_BSD);
    bf16* kx  = (bf16*)(ws + 1 * SZ_BSD);
    bf16* vx  = (bf16*)(ws + 2 * SZ_BSD);
    bf16* wqT = (bf16*)(ws + 3 * SZ_BSD + 0 * SZ_W);
    bf16* wkT = (bf16*)(ws + 3 * SZ_BSD + 1 * SZ_W);
    bf16* wvT = (bf16*)(ws + 3 * SZ_BSD + 2 * SZ_W);
    bf16* woT = (bf16*)(ws + 3 * SZ_BSD + 3 * SZ_W);
    bf16* qp  = (bf16*)(ws + 3 * SZ_BSD + 4 * SZ_W);
    bf16* kp  = (bf16*)(ws + 4 * SZ_BSD + 4 * SZ_W);
    bf16* vp  = (bf16*)(ws + 5 * SZ_BSD + 4 * SZ_W);
    // aliases over dead buffers (qx,kx dead after QKV projection GEMM):
    bf16* vTr = (bf16*)(ws + 0 * SZ_BSD);  // over qx
    bf16* op  = (bf16*)(ws + 1 * SZ_BSD);  // over kx
    // total ws footprint: 6*8MiB + 4*2MiB = 56 MiB

    // 1. convert q,k,v -> bf16
    convert_kernel<<<4096, 256, 0, stream>>>(query, key_, value, qx, kx, vx);
    // 2. transpose+convert weights -> [N,K] bf16
    wtrans_kernel<<<dim3(32, 32, 4), dim3(32, 8), 0, stream>>>(Wq, Wk, Wv, Wo, wqT, wkT, wvT, woT);
    // 3. QKV projections (fused by z)
    gemm_bias_kernel<0><<<dim3(8, 32, 3), 256, 0, stream>>>(
        qx, kx, vx, wqT, wkT, wvT, bq, bk, bv, qp, kp, vp);
    // 4. per-head transpose of V
    vtrans_kernel<<<dim3(32, 32), 256, 0, stream>>>(vp, vTr);
    // 5. attention (writes attn fp32 + op bf16)
    attn_kernel<<<dim3(32, 32), 256, 0, stream>>>(qp, kp, vTr, attn, op);
    // 6. output projection -> fp32 d_out
    gemm_bias_kernel<1><<<dim3(8, 32, 1), 256, 0, stream>>>(
        op, op, op, woT, woT, woT, bo, bo, bo, out, out, out);
}